// Round 5
// baseline (170.852 us; speedup 1.0000x reference)
//
#include <hip/hip_runtime.h>

// Cross_LocalAttention: windowed attention + LePE depthwise conv.
// B=8, H=W=128, DIM=256, HEADS=8, HD=32, window 8x8 (WS=64).
// One block (256 threads, 4 waves) per (window, head): 16384 blocks.
// Q and K fragments are loaded DIRECT to registers (no LDS, no barrier
// dependency); only V goes through LDS (transpose needed for PV + conv).
// The single __syncthreads guards V staging only and sits after
// QK^T+softmax, so V latency hides under matrix/softmax work.
// Swapped-operand QK^T (mfma(K,Q)) puts a full P-row in each lane; the V
// token permutation sp() makes the PV A-frag a pure intra-lane repack.

#define SCALE_F 0.17677669529663687f  // 32^-0.5

typedef __attribute__((ext_vector_type(8))) short bf16x8;
typedef __attribute__((ext_vector_type(4))) float f32x4;
typedef __attribute__((ext_vector_type(4))) unsigned int u32x4;

static __device__ __forceinline__ unsigned short f2bf(float f) {  // RNE
    unsigned u = __builtin_bit_cast(unsigned, f);
    u += 0x7fffu + ((u >> 16) & 1u);
    return (unsigned short)(u >> 16);
}
static __device__ __forceinline__ unsigned pack2(float a, float b) {
    return (unsigned)f2bf(a) | ((unsigned)f2bf(b) << 16);
}
static __device__ __forceinline__ float bf2f_lo(unsigned u) {  // low half
    return __builtin_bit_cast(float, u << 16);
}
static __device__ __forceinline__ float bf2f_hi(unsigned u) {  // high half
    return __builtin_bit_cast(float, u & 0xffff0000u);
}

__global__ __launch_bounds__(256, 5) void lepe_attn_kernel(
    const float* __restrict__ qkv,
    const float* __restrict__ lw,
    const float* __restrict__ lb,
    float* __restrict__ out)
{
    const int bid  = blockIdx.x;
    const int head = bid & 7;
    const int win  = bid >> 3;
    const int ww   = win & 15;
    const int wh   = (win >> 4) & 15;
    const int b    = win >> 8;
    const int t    = threadIdx.x;

    // LDS: only V + conv weights, 10.6 KB.
    __shared__ __align__(16) short v_t[32][72];       // V^T, perm'd token axis
    __shared__ __align__(16) unsigned v_pair[64][18]; // (ch c | ch c+16) packed
    __shared__ float w_s[288];
    __shared__ float b_s[32];

    const float* Qp = qkv;
    const float* Kp = qkv + (size_t)33554432;   // 8*16384*256
    const float* Vp = qkv + (size_t)67108864;
    float* xout = out;
    float* qout = out + (size_t)33554432;

    // float offset of token (0,0) of this window's head-slice
    const size_t wbase = ((size_t)(b * 16384 + (wh * 8) * 128 + ww * 8)) * 256
                       + head * 32;
    // token s lives at wbase + ((s>>3)*128 + (s&7))*256

    const int lane = t & 63;
    const int wid  = t >> 6;
    const int c    = lane & 15;
    const int g    = lane >> 4;
    const int i0   = wid * 16;

    // ---- issue all global loads up front (Q, K, V, weights) ----
    // Q: this wave's fragment rows (token i0+c, dims g*8..g*8+7)
    const int sq = i0 + c;
    const float* qptr = Qp + wbase + ((sq >> 3) * 128 + (sq & 7)) * 256 + g * 8;
    float4 q0 = *(const float4*)(qptr);
    float4 q1 = *(const float4*)(qptr + 4);

    // K: all 4 j-tile fragments (token jt*16+c, dims g*8..g*8+7)
    float4 k0[4], k1[4];
    #pragma unroll
    for (int jt = 0; jt < 4; ++jt) {
        const int sk = jt * 16 + c;
        const float* kptr = Kp + wbase
                          + ((sk >> 3) * 128 + (sk & 7)) * 256 + g * 8;
        k0[jt] = *(const float4*)(kptr);
        k1[jt] = *(const float4*)(kptr + 4);
    }

    // V: cooperative staging loads (consumed after QK^T)
    float4 v04[2];
    #pragma unroll
    for (int u = 0; u < 2; ++u) {
        const int idx = t + u * 256;
        const int s   = idx >> 3;
        const int d4  = idx & 7;
        v04[u] = *(const float4*)(Vp + wbase
                 + ((s >> 3) * 128 + (s & 7)) * 256 + d4 * 4);
    }

    for (int i = t; i < 288; i += 256) w_s[i] = lw[head * 288 + i];
    if (t < 32) b_s[t] = lb[head * 32 + t];

    // ---- Q: scale, emit q-output (exact fp32), pack bf16 fragment ----
    q0.x *= SCALE_F; q0.y *= SCALE_F; q0.z *= SCALE_F; q0.w *= SCALE_F;
    q1.x *= SCALE_F; q1.y *= SCALE_F; q1.z *= SCALE_F; q1.w *= SCALE_F;
    {
        float* qo = qout + ((size_t)bid * 64 + sq) * 32 + g * 8;
        *(float4*)(qo)     = q0;
        *(float4*)(qo + 4) = q1;
    }
    const u32x4 qw = {pack2(q0.x, q0.y), pack2(q0.z, q0.w),
                      pack2(q1.x, q1.y), pack2(q1.z, q1.w)};
    const bf16x8 bq = __builtin_bit_cast(bf16x8, qw);

    bf16x8 ak[4];
    #pragma unroll
    for (int jt = 0; jt < 4; ++jt) {
        const u32x4 kw = {pack2(k0[jt].x, k0[jt].y), pack2(k0[jt].z, k0[jt].w),
                          pack2(k1[jt].x, k1[jt].y), pack2(k1[jt].z, k1[jt].w)};
        ak[jt] = __builtin_bit_cast(bf16x8, kw);
    }

    // ---- QK^T swapped: S[16jt+4g+r][i0+c] in lane(c,g) reg r of tile jt
    f32x4 sacc[4];
    #pragma unroll
    for (int jt = 0; jt < 4; ++jt) {
        f32x4 acc = {0.f, 0.f, 0.f, 0.f};
        sacc[jt] = __builtin_amdgcn_mfma_f32_16x16x32_bf16(ak[jt], bq, acc, 0, 0, 0);
    }

    // ---- V pack into LDS (V loads have had QK^T's latency to land)
    #pragma unroll
    for (int u = 0; u < 2; ++u) {
        const int idx = t + u * 256;
        const int s   = idx >> 3;
        const int d4  = idx & 7;
        const float4 fv = v04[u];
        const unsigned short b0 = f2bf(fv.x), b1 = f2bf(fv.y),
                             b2 = f2bf(fv.z), b3 = f2bf(fv.w);
        const int sp = ((s >> 1) & 1) * 32 + ((s >> 2) & 3) * 8
                     + (s & 1) * 4 + (s >> 4);
        v_t[d4 * 4 + 0][sp] = (short)b0;
        v_t[d4 * 4 + 1][sp] = (short)b1;
        v_t[d4 * 4 + 2][sp] = (short)b2;
        v_t[d4 * 4 + 3][sp] = (short)b3;
        const unsigned short vb[4] = {b0, b1, b2, b3};
        #pragma unroll
        for (int j = 0; j < 4; ++j) {
            const int ch = d4 * 4 + j;
            ((unsigned short*)&v_pair[s][ch & 15])[ch >> 4] = vb[j];
        }
    }

    // ---- softmax: row i0+c spread over lanes {c, c+16, c+32, c+48}
    float mx = -3.0e38f;
    #pragma unroll
    for (int jt = 0; jt < 4; ++jt)
        #pragma unroll
        for (int r = 0; r < 4; ++r)
            mx = fmaxf(mx, sacc[jt][r]);
    mx = fmaxf(mx, __shfl_xor(mx, 16));
    mx = fmaxf(mx, __shfl_xor(mx, 32));

    float p[4][4];
    float sm = 0.f;
    #pragma unroll
    for (int jt = 0; jt < 4; ++jt)
        #pragma unroll
        for (int r = 0; r < 4; ++r) {
            p[jt][r] = __expf(sacc[jt][r] - mx);
            sm += p[jt][r];
        }
    sm += __shfl_xor(sm, 16);
    sm += __shfl_xor(sm, 32);
    const float inv = 1.0f / sm;

    // pack P rows to bf16; A-frags are intra-lane by construction of sp():
    // element e of step ks: P[i0+c][16(e&3)+4g+2ks+(e>>2)]
    unsigned dwA[4], dwB[4];
    #pragma unroll
    for (int r = 0; r < 4; ++r) {
        dwA[r] = pack2(p[0][r] * inv, p[1][r] * inv);
        dwB[r] = pack2(p[2][r] * inv, p[3][r] * inv);
    }
    const u32x4 w0 = {dwA[0], dwB[0], dwA[1], dwB[1]};
    const u32x4 w1 = {dwA[2], dwB[2], dwA[3], dwB[3]};
    const bf16x8 pa0 = __builtin_bit_cast(bf16x8, w0);
    const bf16x8 pa1 = __builtin_bit_cast(bf16x8, w1);

    __syncthreads();   // V staged (the only cross-wave dependency)

    // ---- PV
    f32x4 o0 = {0.f, 0.f, 0.f, 0.f};
    f32x4 o1 = {0.f, 0.f, 0.f, 0.f};
    {
        const bf16x8 vb00 = *(const bf16x8*)&v_t[c][g * 8];
        const bf16x8 vb10 = *(const bf16x8*)&v_t[16 + c][g * 8];
        const bf16x8 vb01 = *(const bf16x8*)&v_t[c][32 + g * 8];
        const bf16x8 vb11 = *(const bf16x8*)&v_t[16 + c][32 + g * 8];
        o0 = __builtin_amdgcn_mfma_f32_16x16x32_bf16(pa0, vb00, o0, 0, 0, 0);
        o1 = __builtin_amdgcn_mfma_f32_16x16x32_bf16(pa0, vb10, o1, 0, 0, 0);
        o0 = __builtin_amdgcn_mfma_f32_16x16x32_bf16(pa1, vb01, o0, 0, 0, 0);
        o1 = __builtin_amdgcn_mfma_f32_16x16x32_bf16(pa1, vb11, o1, 0, 0, 0);
    }

    // ---- fused LePE conv + epilogue.
    // Lane's 4 output tokens: s = i0+4g+r -> window row srow, cols scol0+r.
    const int srow  = 2 * wid + (g >> 1);
    const int scol0 = 4 * (g & 1);

    unsigned pr[3][6];
    #pragma unroll
    for (int dy = 0; dy < 3; ++dy) {
        const int rr   = srow + dy - 1;
        const bool rok = (rr >= 0) && (rr < 8);
        const int rcl  = rok ? rr : 0;
        #pragma unroll
        for (int dx = 0; dx < 6; ++dx) {
            const int cc   = scol0 + dx - 1;
            const bool cok = (cc >= 0) && (cc < 8);
            const int ccl  = cok ? cc : 0;
            const unsigned val = v_pair[rcl * 8 + ccl][c];
            pr[dy][dx] = (rok && cok) ? val : 0u;
        }
    }
    #pragma unroll
    for (int half = 0; half < 2; ++half) {
        const int ch = c + 16 * half;
        float wv[9];
        #pragma unroll
        for (int k2 = 0; k2 < 9; ++k2) wv[k2] = w_s[ch * 9 + k2];
        float acc[4] = {b_s[ch], b_s[ch], b_s[ch], b_s[ch]};
        #pragma unroll
        for (int dy = 0; dy < 3; ++dy) {
            float rowv[6];
            #pragma unroll
            for (int dx = 0; dx < 6; ++dx)
                rowv[dx] = half ? bf2f_hi(pr[dy][dx]) : bf2f_lo(pr[dy][dx]);
            #pragma unroll
            for (int r = 0; r < 4; ++r)
                #pragma unroll
                for (int dk = 0; dk < 3; ++dk)
                    acc[r] += wv[dy * 3 + dk] * rowv[r + dk];
        }
        #pragma unroll
        for (int r = 0; r < 4; ++r) {
            if (half == 0) o0[r] += acc[r]; else o1[r] += acc[r];
        }
    }

    #pragma unroll
    for (int r = 0; r < 4; ++r) {
        const int s   = i0 + 4 * g + r;
        const int row = wh * 8 + (s >> 3);
        const int col = ww * 8 + (s & 7);
        float* xo = xout + ((size_t)(b * 16384 + row * 128 + col)) * 256
                  + head * 32;
        xo[c]      = o0[r];
        xo[16 + c] = o1[r];
    }
}

extern "C" void kernel_launch(void* const* d_in, const int* in_sizes, int n_in,
                              void* d_out, int out_size, void* d_ws, size_t ws_size,
                              hipStream_t stream) {
    (void)in_sizes; (void)n_in; (void)out_size; (void)d_ws; (void)ws_size;
    const float* qkv = (const float*)d_in[0];
    const float* lw  = (const float*)d_in[1];
    const float* lb  = (const float*)d_in[2];
    float* out = (float*)d_out;
    lepe_attn_kernel<<<dim3(16384), dim3(256), 0, stream>>>(qkv, lw, lb, out);
}

// Round 6
// 169.071 us; speedup vs baseline: 1.0105x; 1.0105x over previous
//
#include <hip/hip_runtime.h>

// Cross_LocalAttention: windowed attention + LePE depthwise conv.
// B=8, H=W=128, DIM=256, HEADS=8, HD=32, window 8x8 (WS=64).
// 4096 blocks x 256 threads; each block keeps one head and processes
// PAIRS=4 consecutive windows, register-prefetching window i+1's q/k/v
// while staging/computing window i (keeps HBM loads in flight through
// compute phases and across former block boundaries).
// Per window: stage q/k (bf16) + v (transposed/perm'd + packed pairs) in
// LDS; swapped-operand QK^T (mfma(K,Q)) puts a full P-row in each lane;
// the V token permutation sp() makes the PV A-frag a pure intra-lane
// repack; LePE conv fused into the epilogue.

#define SCALE_F 0.17677669529663687f  // 32^-0.5
#define PAIRS 4

typedef __attribute__((ext_vector_type(8))) short bf16x8;
typedef __attribute__((ext_vector_type(4))) float f32x4;
typedef __attribute__((ext_vector_type(4))) unsigned int u32x4;

static __device__ __forceinline__ unsigned short f2bf(float f) {  // RNE
    unsigned u = __builtin_bit_cast(unsigned, f);
    u += 0x7fffu + ((u >> 16) & 1u);
    return (unsigned short)(u >> 16);
}
static __device__ __forceinline__ unsigned pack2(float a, float b) {
    return (unsigned)f2bf(a) | ((unsigned)f2bf(b) << 16);
}
static __device__ __forceinline__ float bf2f_lo(unsigned u) {
    return __builtin_bit_cast(float, u << 16);
}
static __device__ __forceinline__ float bf2f_hi(unsigned u) {
    return __builtin_bit_cast(float, u & 0xffff0000u);
}

__global__ __launch_bounds__(256, 5) void lepe_attn_kernel(
    const float* __restrict__ qkv,
    const float* __restrict__ lw,
    const float* __restrict__ lb,
    float* __restrict__ out)
{
    const int head = blockIdx.x & 7;
    const int wg   = blockIdx.x >> 3;       // window group, 512 groups
    const int t    = threadIdx.x;

    // LDS: 20.7 KB -> 5 blocks/CU. Strides keep b128 reads 16B-aligned,
    // <=2-way bank aliasing (free per m136).
    __shared__ __align__(16) short q_s[64][40];
    __shared__ __align__(16) short k_s[64][40];
    __shared__ __align__(16) short v_t[32][72];       // V^T, perm'd tokens
    __shared__ __align__(16) unsigned v_pair[64][18]; // (ch c | ch c+16)
    __shared__ float w_s[288];
    __shared__ float b_s[32];

    const float* Qp = qkv;
    const float* Kp = qkv + (size_t)33554432;   // 8*16384*256
    const float* Vp = qkv + (size_t)67108864;
    float* xout = out;
    float* qout = out + (size_t)33554432;

    for (int i = t; i < 288; i += 256) w_s[i] = lw[head * 288 + i];
    if (t < 32) b_s[t] = lb[head * 32 + t];

    // staging decomposition: unit u covers token s = s0+32u, dims d4*4..+3
    const int s0 = t >> 3;
    const int d4 = t & 7;

    const int lane = t & 63;
    const int wid  = t >> 6;
    const int c    = lane & 15;
    const int g    = lane >> 4;
    const int i0   = wid * 16;

    // per-window head-slice base (float index) for a given window id
    auto wbase = [&](int win) -> size_t {
        const int ww = win & 15;
        const int wh = (win >> 4) & 15;
        const int b  = win >> 8;
        return ((size_t)(b * 16384 + (wh * 8) * 128 + ww * 8)) * 256
             + head * 32;
    };
    // token offset within a window's head slice
    auto toff = [&](int s) -> int { return ((s >> 3) * 128 + (s & 7)) * 256; };

    // ---- prologue: load window 0 into registers
    float4 cq[2], ck[2], cv[2];
    {
        const size_t base = wbase(wg * PAIRS);
        #pragma unroll
        for (int u = 0; u < 2; ++u) {
            const int s = s0 + 32 * u;
            const size_t goff = base + toff(s) + d4 * 4;
            cq[u] = *(const float4*)(Qp + goff);
            ck[u] = *(const float4*)(Kp + goff);
            cv[u] = *(const float4*)(Vp + goff);
        }
    }

    #pragma unroll
    for (int it = 0; it < PAIRS; ++it) {
        const int win = wg * PAIRS + it;
        const int bid = win * 8 + head;

        // ---- issue next window's loads (in flight through this window's
        // staging + compute)
        float4 nq[2], nk[2], nv[2];
        if (it + 1 < PAIRS) {
            const size_t base = wbase(win + 1);
            #pragma unroll
            for (int u = 0; u < 2; ++u) {
                const int s = s0 + 32 * u;
                const size_t goff = base + toff(s) + d4 * 4;
                nq[u] = *(const float4*)(Qp + goff);
                nk[u] = *(const float4*)(Kp + goff);
                nv[u] = *(const float4*)(Vp + goff);
            }
        }

        // ---- stage current window to LDS (+ q output, exact fp32)
        #pragma unroll
        for (int u = 0; u < 2; ++u) {
            const int s = s0 + 32 * u;
            float4 fq = cq[u];
            fq.x *= SCALE_F; fq.y *= SCALE_F; fq.z *= SCALE_F; fq.w *= SCALE_F;
            *(float4*)(qout + ((size_t)bid * 64 + s) * 32 + d4 * 4) = fq;

            uint2 qp, kp;
            qp.x = pack2(fq.x, fq.y);
            qp.y = pack2(fq.z, fq.w);
            kp.x = pack2(ck[u].x, ck[u].y);
            kp.y = pack2(ck[u].z, ck[u].w);
            *(uint2*)&q_s[s][d4 * 4] = qp;
            *(uint2*)&k_s[s][d4 * 4] = kp;

            const float4 fv = cv[u];
            const unsigned short b0 = f2bf(fv.x), b1 = f2bf(fv.y),
                                 b2 = f2bf(fv.z), b3 = f2bf(fv.w);
            const int sp = ((s >> 1) & 1) * 32 + ((s >> 2) & 3) * 8
                         + (s & 1) * 4 + (s >> 4);
            v_t[d4 * 4 + 0][sp] = (short)b0;
            v_t[d4 * 4 + 1][sp] = (short)b1;
            v_t[d4 * 4 + 2][sp] = (short)b2;
            v_t[d4 * 4 + 3][sp] = (short)b3;
            const unsigned short vb[4] = {b0, b1, b2, b3};
            #pragma unroll
            for (int j = 0; j < 4; ++j) {
                const int ch = d4 * 4 + j;
                ((unsigned short*)&v_pair[s][ch & 15])[ch >> 4] = vb[j];
            }
        }
        __syncthreads();

        // ---- QK^T swapped: lane(c,g) reg r of tile jt = S[16jt+4g+r][i0+c]
        const bf16x8 bq = *(const bf16x8*)&q_s[i0 + c][g * 8];
        f32x4 sacc[4];
        #pragma unroll
        for (int jt = 0; jt < 4; ++jt) {
            const bf16x8 ak = *(const bf16x8*)&k_s[jt * 16 + c][g * 8];
            f32x4 acc = {0.f, 0.f, 0.f, 0.f};
            sacc[jt] = __builtin_amdgcn_mfma_f32_16x16x32_bf16(ak, bq, acc,
                                                               0, 0, 0);
        }

        // ---- softmax: row i0+c spread over lanes {c, c+16, c+32, c+48}
        float mx = -3.0e38f;
        #pragma unroll
        for (int jt = 0; jt < 4; ++jt)
            #pragma unroll
            for (int r = 0; r < 4; ++r)
                mx = fmaxf(mx, sacc[jt][r]);
        mx = fmaxf(mx, __shfl_xor(mx, 16));
        mx = fmaxf(mx, __shfl_xor(mx, 32));

        float p[4][4];
        float sm = 0.f;
        #pragma unroll
        for (int jt = 0; jt < 4; ++jt)
            #pragma unroll
            for (int r = 0; r < 4; ++r) {
                p[jt][r] = __expf(sacc[jt][r] - mx);
                sm += p[jt][r];
            }
        sm += __shfl_xor(sm, 16);
        sm += __shfl_xor(sm, 32);
        const float inv = 1.0f / sm;

        // pack P rows to bf16; A-frags intra-lane by construction of sp():
        // element e of step ks: P[i0+c][16(e&3)+4g+2ks+(e>>2)]
        unsigned dwA[4], dwB[4];
        #pragma unroll
        for (int r = 0; r < 4; ++r) {
            dwA[r] = pack2(p[0][r] * inv, p[1][r] * inv);
            dwB[r] = pack2(p[2][r] * inv, p[3][r] * inv);
        }
        const u32x4 w0 = {dwA[0], dwB[0], dwA[1], dwB[1]};
        const u32x4 w1 = {dwA[2], dwB[2], dwA[3], dwB[3]};
        const bf16x8 pa0 = __builtin_bit_cast(bf16x8, w0);
        const bf16x8 pa1 = __builtin_bit_cast(bf16x8, w1);

        // ---- PV
        f32x4 o0 = {0.f, 0.f, 0.f, 0.f};
        f32x4 o1 = {0.f, 0.f, 0.f, 0.f};
        {
            const bf16x8 vb00 = *(const bf16x8*)&v_t[c][g * 8];
            const bf16x8 vb10 = *(const bf16x8*)&v_t[16 + c][g * 8];
            const bf16x8 vb01 = *(const bf16x8*)&v_t[c][32 + g * 8];
            const bf16x8 vb11 = *(const bf16x8*)&v_t[16 + c][32 + g * 8];
            o0 = __builtin_amdgcn_mfma_f32_16x16x32_bf16(pa0, vb00, o0, 0, 0, 0);
            o1 = __builtin_amdgcn_mfma_f32_16x16x32_bf16(pa0, vb10, o1, 0, 0, 0);
            o0 = __builtin_amdgcn_mfma_f32_16x16x32_bf16(pa1, vb01, o0, 0, 0, 0);
            o1 = __builtin_amdgcn_mfma_f32_16x16x32_bf16(pa1, vb11, o1, 0, 0, 0);
        }

        // ---- fused LePE conv. Lane's 4 tokens: s = i0+4g+r -> window row
        // srow, cols scol0+r.
        const int srow  = 2 * wid + (g >> 1);
        const int scol0 = 4 * (g & 1);

        unsigned pr[3][6];
        #pragma unroll
        for (int dy = 0; dy < 3; ++dy) {
            const int rr   = srow + dy - 1;
            const bool rok = (rr >= 0) && (rr < 8);
            const int rcl  = rok ? rr : 0;
            #pragma unroll
            for (int dx = 0; dx < 6; ++dx) {
                const int cc   = scol0 + dx - 1;
                const bool cok = (cc >= 0) && (cc < 8);
                const int ccl  = cok ? cc : 0;
                const unsigned val = v_pair[rcl * 8 + ccl][c];
                pr[dy][dx] = (rok && cok) ? val : 0u;
            }
        }
        #pragma unroll
        for (int half = 0; half < 2; ++half) {
            const int ch = c + 16 * half;
            float wv[9];
            #pragma unroll
            for (int k2 = 0; k2 < 9; ++k2) wv[k2] = w_s[ch * 9 + k2];
            float acc[4] = {b_s[ch], b_s[ch], b_s[ch], b_s[ch]};
            #pragma unroll
            for (int dy = 0; dy < 3; ++dy) {
                float rowv[6];
                #pragma unroll
                for (int dx = 0; dx < 6; ++dx)
                    rowv[dx] = half ? bf2f_hi(pr[dy][dx]) : bf2f_lo(pr[dy][dx]);
                #pragma unroll
                for (int r = 0; r < 4; ++r)
                    #pragma unroll
                    for (int dk = 0; dk < 3; ++dk)
                        acc[r] += wv[dy * 3 + dk] * rowv[r + dk];
            }
            #pragma unroll
            for (int r = 0; r < 4; ++r) {
                if (half == 0) o0[r] += acc[r]; else o1[r] += acc[r];
            }
        }

        // ---- x output
        const size_t xbase = wbase(win);
        #pragma unroll
        for (int r = 0; r < 4; ++r) {
            const int s = i0 + 4 * g + r;
            float* xo = xout + xbase + toff(s);
            xo[c]      = o0[r];
            xo[16 + c] = o1[r];
        }

        // ---- rotate prefetched registers; protect LDS reuse
        if (it + 1 < PAIRS) {
            __syncthreads();
            #pragma unroll
            for (int u = 0; u < 2; ++u) {
                cq[u] = nq[u]; ck[u] = nk[u]; cv[u] = nv[u];
            }
        }
    }
}

extern "C" void kernel_launch(void* const* d_in, const int* in_sizes, int n_in,
                              void* d_out, int out_size, void* d_ws, size_t ws_size,
                              hipStream_t stream) {
    (void)in_sizes; (void)n_in; (void)out_size; (void)d_ws; (void)ws_size;
    const float* qkv = (const float*)d_in[0];
    const float* lw  = (const float*)d_in[1];
    const float* lb  = (const float*)d_in[2];
    float* out = (float*)d_out;
    lepe_attn_kernel<<<dim3(4096), dim3(256), 0, stream>>>(qkv, lw, lb, out);
}

// Round 7
// 146.050 us; speedup vs baseline: 1.1698x; 1.1576x over previous
//
#include <hip/hip_runtime.h>

// Cross_LocalAttention: windowed attention + LePE depthwise conv.
// B=8, H=W=128, DIM=256, HEADS=8, HD=32, window 8x8 (WS=64).
// One block (256 threads, 4 waves) per (window, head): 16384 blocks.
// K,V staged via LDS (K is read by all 4 waves; V needs transpose for PV
// + conv). Q is wave-private: loaded DIRECT to registers (128B-coalesced),
// scaled, written to qout, packed to the MFMA B-frag -- no LDS, no barrier
// dependency. The single __syncthreads covers only K/V staging.
// Swapped-operand QK^T (mfma(K,Q)) puts a full P-row in each lane; the V
// token permutation sp() makes the PV A-frag a pure intra-lane repack.
// Conv reads packed channel-pairs (ch c | ch c+16) so one ds_read_b32
// feeds both output halves. LePE conv fused into the epilogue.

#define SCALE_F 0.17677669529663687f  // 32^-0.5

typedef __attribute__((ext_vector_type(8))) short bf16x8;
typedef __attribute__((ext_vector_type(4))) float f32x4;
typedef __attribute__((ext_vector_type(4))) unsigned int u32x4;

static __device__ __forceinline__ unsigned short f2bf(float f) {  // RNE
    unsigned u = __builtin_bit_cast(unsigned, f);
    u += 0x7fffu + ((u >> 16) & 1u);
    return (unsigned short)(u >> 16);
}
static __device__ __forceinline__ unsigned pack2(float a, float b) {
    return (unsigned)f2bf(a) | ((unsigned)f2bf(b) << 16);
}
static __device__ __forceinline__ float bf2f_lo(unsigned u) {
    return __builtin_bit_cast(float, u << 16);
}
static __device__ __forceinline__ float bf2f_hi(unsigned u) {
    return __builtin_bit_cast(float, u & 0xffff0000u);
}

__global__ __launch_bounds__(256, 5) void lepe_attn_kernel(
    const float* __restrict__ qkv,
    const float* __restrict__ lw,
    const float* __restrict__ lb,
    float* __restrict__ out)
{
    const int bid  = blockIdx.x;
    const int head = bid & 7;
    const int win  = bid >> 3;
    const int ww   = win & 15;
    const int wh   = (win >> 4) & 15;
    const int b    = win >> 8;
    const int t    = threadIdx.x;

    // LDS: ~15.6 KB. Strides keep b128 reads 16B-aligned, <=2-way bank
    // aliasing (free per m136).
    __shared__ __align__(16) short k_s[64][40];
    __shared__ __align__(16) short v_t[32][72];       // V^T, perm'd tokens
    __shared__ __align__(16) unsigned v_pair[64][18]; // (ch c | ch c+16)
    __shared__ float w_s[288];
    __shared__ float b_s[32];

    const float* Qp = qkv;
    const float* Kp = qkv + (size_t)33554432;   // 8*16384*256
    const float* Vp = qkv + (size_t)67108864;
    float* xout = out;
    float* qout = out + (size_t)33554432;

    // float offset of token (0,0) of this window's head-slice
    const size_t wbase = ((size_t)(b * 16384 + (wh * 8) * 128 + ww * 8)) * 256
                       + head * 32;
    // token s lives at wbase + ((s>>3)*128 + (s&7))*256

    const int lane = t & 63;
    const int wid  = t >> 6;
    const int c    = lane & 15;
    const int g    = lane >> 4;
    const int i0   = wid * 16;

    // ---- issue K,V staging loads first (barrier path)
    const int s0 = t >> 3;
    const int d4 = t & 7;
    float4 ck[2], cv[2];
    #pragma unroll
    for (int u = 0; u < 2; ++u) {
        const int s = s0 + 32 * u;
        const size_t goff = wbase + ((s >> 3) * 128 + (s & 7)) * 256 + d4 * 4;
        ck[u] = *(const float4*)(Kp + goff);
        cv[u] = *(const float4*)(Vp + goff);
    }

    // ---- issue Q loads (wave-private, no barrier dependency)
    const int sq = i0 + c;
    const float* qptr = Qp + wbase + ((sq >> 3) * 128 + (sq & 7)) * 256 + g * 8;
    float4 q0 = *(const float4*)(qptr);
    float4 q1 = *(const float4*)(qptr + 4);

    for (int i = t; i < 288; i += 256) w_s[i] = lw[head * 288 + i];
    if (t < 32) b_s[t] = lb[head * 32 + t];

    // ---- stage K,V to LDS
    #pragma unroll
    for (int u = 0; u < 2; ++u) {
        const int s = s0 + 32 * u;
        uint2 kp;
        kp.x = pack2(ck[u].x, ck[u].y);
        kp.y = pack2(ck[u].z, ck[u].w);
        *(uint2*)&k_s[s][d4 * 4] = kp;

        const float4 fv = cv[u];
        const unsigned short b0 = f2bf(fv.x), b1 = f2bf(fv.y),
                             b2 = f2bf(fv.z), b3 = f2bf(fv.w);
        const int sp = ((s >> 1) & 1) * 32 + ((s >> 2) & 3) * 8
                     + (s & 1) * 4 + (s >> 4);
        v_t[d4 * 4 + 0][sp] = (short)b0;
        v_t[d4 * 4 + 1][sp] = (short)b1;
        v_t[d4 * 4 + 2][sp] = (short)b2;
        v_t[d4 * 4 + 3][sp] = (short)b3;
        const unsigned short vb[4] = {b0, b1, b2, b3};
        #pragma unroll
        for (int j = 0; j < 4; ++j) {
            const int ch = d4 * 4 + j;
            ((unsigned short*)&v_pair[s][ch & 15])[ch >> 4] = vb[j];
        }
    }

    // ---- Q: scale, emit q-output (exact fp32), pack MFMA B-frag
    q0.x *= SCALE_F; q0.y *= SCALE_F; q0.z *= SCALE_F; q0.w *= SCALE_F;
    q1.x *= SCALE_F; q1.y *= SCALE_F; q1.z *= SCALE_F; q1.w *= SCALE_F;
    {
        float* qo = qout + ((size_t)bid * 64 + sq) * 32 + g * 8;
        *(float4*)(qo)     = q0;
        *(float4*)(qo + 4) = q1;
    }
    const u32x4 qw = {pack2(q0.x, q0.y), pack2(q0.z, q0.w),
                      pack2(q1.x, q1.y), pack2(q1.z, q1.w)};
    const bf16x8 bq = __builtin_bit_cast(bf16x8, qw);

    __syncthreads();   // K,V staged

    // ---- QK^T swapped: lane(c,g) reg r of tile jt = S[16jt+4g+r][i0+c]
    f32x4 sacc[4];
    #pragma unroll
    for (int jt = 0; jt < 4; ++jt) {
        const bf16x8 ak = *(const bf16x8*)&k_s[jt * 16 + c][g * 8];
        f32x4 acc = {0.f, 0.f, 0.f, 0.f};
        sacc[jt] = __builtin_amdgcn_mfma_f32_16x16x32_bf16(ak, bq, acc, 0, 0, 0);
    }

    // ---- softmax: row i0+c spread over lanes {c, c+16, c+32, c+48}
    float mx = -3.0e38f;
    #pragma unroll
    for (int jt = 0; jt < 4; ++jt)
        #pragma unroll
        for (int r = 0; r < 4; ++r)
            mx = fmaxf(mx, sacc[jt][r]);
    mx = fmaxf(mx, __shfl_xor(mx, 16));
    mx = fmaxf(mx, __shfl_xor(mx, 32));

    float p[4][4];
    float sm = 0.f;
    #pragma unroll
    for (int jt = 0; jt < 4; ++jt)
        #pragma unroll
        for (int r = 0; r < 4; ++r) {
            p[jt][r] = __expf(sacc[jt][r] - mx);
            sm += p[jt][r];
        }
    sm += __shfl_xor(sm, 16);
    sm += __shfl_xor(sm, 32);
    const float inv = 1.0f / sm;

    // pack P rows to bf16; A-frags intra-lane by construction of sp():
    // element e of step ks: P[i0+c][16(e&3)+4g+2ks+(e>>2)]
    unsigned dwA[4], dwB[4];
    #pragma unroll
    for (int r = 0; r < 4; ++r) {
        dwA[r] = pack2(p[0][r] * inv, p[1][r] * inv);
        dwB[r] = pack2(p[2][r] * inv, p[3][r] * inv);
    }
    const u32x4 w0 = {dwA[0], dwB[0], dwA[1], dwB[1]};
    const u32x4 w1 = {dwA[2], dwB[2], dwA[3], dwB[3]};
    const bf16x8 pa0 = __builtin_bit_cast(bf16x8, w0);
    const bf16x8 pa1 = __builtin_bit_cast(bf16x8, w1);

    // ---- PV
    f32x4 o0 = {0.f, 0.f, 0.f, 0.f};
    f32x4 o1 = {0.f, 0.f, 0.f, 0.f};
    {
        const bf16x8 vb00 = *(const bf16x8*)&v_t[c][g * 8];
        const bf16x8 vb10 = *(const bf16x8*)&v_t[16 + c][g * 8];
        const bf16x8 vb01 = *(const bf16x8*)&v_t[c][32 + g * 8];
        const bf16x8 vb11 = *(const bf16x8*)&v_t[16 + c][32 + g * 8];
        o0 = __builtin_amdgcn_mfma_f32_16x16x32_bf16(pa0, vb00, o0, 0, 0, 0);
        o1 = __builtin_amdgcn_mfma_f32_16x16x32_bf16(pa0, vb10, o1, 0, 0, 0);
        o0 = __builtin_amdgcn_mfma_f32_16x16x32_bf16(pa1, vb01, o0, 0, 0, 0);
        o1 = __builtin_amdgcn_mfma_f32_16x16x32_bf16(pa1, vb11, o1, 0, 0, 0);
    }

    // ---- fused LePE conv. Lane's 4 tokens: s = i0+4g+r -> window row srow,
    // cols scol0+r.
    const int srow  = 2 * wid + (g >> 1);
    const int scol0 = 4 * (g & 1);

    unsigned pr[3][6];
    #pragma unroll
    for (int dy = 0; dy < 3; ++dy) {
        const int rr   = srow + dy - 1;
        const bool rok = (rr >= 0) && (rr < 8);
        const int rcl  = rok ? rr : 0;
        #pragma unroll
        for (int dx = 0; dx < 6; ++dx) {
            const int cc   = scol0 + dx - 1;
            const bool cok = (cc >= 0) && (cc < 8);
            const int ccl  = cok ? cc : 0;
            const unsigned val = v_pair[rcl * 8 + ccl][c];
            pr[dy][dx] = (rok && cok) ? val : 0u;
        }
    }
    #pragma unroll
    for (int half = 0; half < 2; ++half) {
        const int ch = c + 16 * half;
        float wv[9];
        #pragma unroll
        for (int k2 = 0; k2 < 9; ++k2) wv[k2] = w_s[ch * 9 + k2];
        float acc[4] = {b_s[ch], b_s[ch], b_s[ch], b_s[ch]};
        #pragma unroll
        for (int dy = 0; dy < 3; ++dy) {
            float rowv[6];
            #pragma unroll
            for (int dx = 0; dx < 6; ++dx)
                rowv[dx] = half ? bf2f_hi(pr[dy][dx]) : bf2f_lo(pr[dy][dx]);
            #pragma unroll
            for (int r = 0; r < 4; ++r)
                #pragma unroll
                for (int dk = 0; dk < 3; ++dk)
                    acc[r] += wv[dy * 3 + dk] * rowv[r + dk];
        }
        #pragma unroll
        for (int r = 0; r < 4; ++r) {
            if (half == 0) o0[r] += acc[r]; else o1[r] += acc[r];
        }
    }

    // ---- x output
    #pragma unroll
    for (int r = 0; r < 4; ++r) {
        const int s = i0 + 4 * g + r;
        float* xo = xout + wbase + ((s >> 3) * 128 + (s & 7)) * 256;
        xo[c]      = o0[r];
        xo[16 + c] = o1[r];
    }
}

extern "C" void kernel_launch(void* const* d_in, const int* in_sizes, int n_in,
                              void* d_out, int out_size, void* d_ws, size_t ws_size,
                              hipStream_t stream) {
    (void)in_sizes; (void)n_in; (void)out_size; (void)d_ws; (void)ws_size;
    const float* qkv = (const float*)d_in[0];
    const float* lw  = (const float*)d_in[1];
    const float* lb  = (const float*)d_in[2];
    float* out = (float*)d_out;
    lepe_attn_kernel<<<dim3(16384), dim3(256), 0, stream>>>(qkv, lw, lb, out);
}